// Round 8
// baseline (285.238 us; speedup 1.0000x reference)
//
#include <hip/hip_runtime.h>
#include <hip/hip_fp16.h>

#define NB    512   // dst buckets (256 nodes each), bucket = dst >> 8
#define BSH   8
#define HBLK  384   // hist blocks in k_setup
#define BBLK  512   // blocks in k_bin

typedef _Float16 f16;
typedef _Float16 half8 __attribute__((ext_vector_type(8)));
typedef __fp16 pk16x2 __attribute__((ext_vector_type(2)));  // cvt_pkrtz return type
typedef float f32x4 __attribute__((ext_vector_type(4)));

// ============================================================
// Setup (fused): blocks 0..127 transpose W/lin_w -> Wt/LWt f16;
// blocks 128.. run the dst-bucket histogram, LDS-aggregated ->
// 512 global atomics per block into btot (pre-zeroed).
// ============================================================
__global__ __launch_bounds__(256) void k_setup(
    const float* __restrict__ W, const float* __restrict__ LW,
    f16* __restrict__ Wt, f16* __restrict__ LWt,
    const int* __restrict__ dst, int* __restrict__ btot, int E, int chunk)
{
    int b = blockIdx.x;
    int t = threadIdx.x;
    if (b < 128) {
        if (t < 128) Wt[b * 128 + t]           = (f16)W[t * 128 + b];
        else         LWt[b * 128 + (t - 128)]  = (f16)LW[(t - 128) * 128 + b];
        return;
    }
    __shared__ int h[NB];
    h[t] = 0; h[t + 256] = 0;
    __syncthreads();
    int blk = b - 128;
    int e0 = blk * chunk;
    int e1 = min(e0 + chunk, E);
    for (int e = e0 + t; e < e1; e += 256)
        atomicAdd(&h[dst[e] >> BSH], 1);
    __syncthreads();
    if (h[t])       atomicAdd(&btot[t], h[t]);
    if (h[t + 256]) atomicAdd(&btot[t + 256], h[t + 256]);
}

// ============================================================
// MFMA GEMM 1: H = x @ W + attention-logit epilogue. Tile 64x128.
// ============================================================
__global__ __launch_bounds__(256) void k_gemm_att(
    const float* __restrict__ A, const f16* __restrict__ Wt,
    const float* __restrict__ att_s, const float* __restrict__ att_d,
    f16* __restrict__ Hh, float* __restrict__ as_out, float* __restrict__ ad_out,
    int M)
{
    __shared__ __align__(16) f16 as_lds[64 * 136];
    int t = threadIdx.x;
    int row0 = blockIdx.x * 64;

    // Stage A: f32 -> f16 packed, [m][k] stride 136
    {
        int r = t >> 2, kq = (t & 3) * 32;
        const float* ap = A + (size_t)(row0 + r) * 128 + kq;
        bool valid = (row0 + r) < M;
        pk16x2 hb[16];
#pragma unroll
        for (int j = 0; j < 8; ++j) {
            float4 v = valid ? *(const float4*)(ap + j * 4) : make_float4(0.f, 0.f, 0.f, 0.f);
            hb[2 * j]     = __builtin_amdgcn_cvt_pkrtz(v.x, v.y);
            hb[2 * j + 1] = __builtin_amdgcn_cvt_pkrtz(v.z, v.w);
        }
        f16* dst = as_lds + r * 136 + kq;
#pragma unroll
        for (int j = 0; j < 4; ++j) *(float4*)(dst + j * 8) = ((float4*)hb)[j];
    }
    __syncthreads();

    int w = t >> 6, ln = t & 63;
    int rr = (w & 1) * 32;
    int cc = (w >> 1) * 64;
    int q = ln >> 4, m = ln & 15;

    f32x4 acc[2][4];
#pragma unroll
    for (int i = 0; i < 2; ++i)
#pragma unroll
        for (int j = 0; j < 4; ++j) acc[i][j] = (f32x4){0.f, 0.f, 0.f, 0.f};

    const f16* wp = Wt + (size_t)(cc + m) * 128 + q * 8;
#pragma unroll
    for (int ks = 0; ks < 4; ++ks) {
        int k0 = ks * 32 + q * 8;
        half8 a0 = *(const half8*)(as_lds + (rr + m) * 136 + k0);
        half8 a1 = *(const half8*)(as_lds + (rr + 16 + m) * 136 + k0);
        half8 bf[4];
#pragma unroll
        for (int j = 0; j < 4; ++j)
            bf[j] = *(const half8*)(wp + j * 16 * 128 + ks * 32);
#pragma unroll
        for (int j = 0; j < 4; ++j) {
            acc[0][j] = __builtin_amdgcn_mfma_f32_16x16x32_f16(a0, bf[j], acc[0][j], 0, 0, 0);
            acc[1][j] = __builtin_amdgcn_mfma_f32_16x16x32_f16(a1, bf[j], acc[1][j], 0, 0, 0);
        }
    }
    __syncthreads();
#pragma unroll
    for (int i = 0; i < 2; ++i)
#pragma unroll
        for (int j = 0; j < 4; ++j)
#pragma unroll
            for (int g = 0; g < 4; ++g)
                as_lds[(rr + i * 16 + q * 4 + g) * 136 + cc + j * 16 + m] = (f16)acc[i][j][g];
    __syncthreads();
    // coalesced H write
    {
        int r = t >> 2, cq = (t & 3) * 32;
        if (row0 + r < M) {
            float4 o0 = *(const float4*)(as_lds + r * 136 + cq);
            float4 o1 = *(const float4*)(as_lds + r * 136 + cq + 8);
            float4 o2 = *(const float4*)(as_lds + r * 136 + cq + 16);
            float4 o3 = *(const float4*)(as_lds + r * 136 + cq + 24);
            float4* hp = (float4*)(Hh + (size_t)(row0 + r) * 128 + cq);
            hp[0] = o0; hp[1] = o1; hp[2] = o2; hp[3] = o3;
        }
    }
    // attention dots
    {
        int rl = w * 16 + m;
        int head = q;
        float ds = 0.f, dd = 0.f;
#pragma unroll
        for (int ch = 0; ch < 4; ++ch) {
            half8 hv = *(const half8*)(as_lds + rl * 136 + head * 32 + ch * 8);
            float4 s0 = *(const float4*)(att_s + head * 32 + ch * 8);
            float4 s1 = *(const float4*)(att_s + head * 32 + ch * 8 + 4);
            float4 d0 = *(const float4*)(att_d + head * 32 + ch * 8);
            float4 d1 = *(const float4*)(att_d + head * 32 + ch * 8 + 4);
            ds += (float)hv[0] * s0.x + (float)hv[1] * s0.y + (float)hv[2] * s0.z + (float)hv[3] * s0.w
                + (float)hv[4] * s1.x + (float)hv[5] * s1.y + (float)hv[6] * s1.z + (float)hv[7] * s1.w;
            dd += (float)hv[0] * d0.x + (float)hv[1] * d0.y + (float)hv[2] * d0.z + (float)hv[3] * d0.w
                + (float)hv[4] * d1.x + (float)hv[5] * d1.y + (float)hv[6] * d1.z + (float)hv[7] * d1.w;
        }
        if (row0 + rl < M) {
            as_out[(row0 + rl) * 4 + head] = ds;
            ad_out[(row0 + rl) * 4 + head] = dd;
        }
    }
}

// ============================================================
// Bin: bucket scatter with per-block range reservation.
// Local exclusive scan of btot (512 entries, 2/thread) -> bases;
// LDS hist of chunk; reserve per-bucket ranges via atomicAdd on
// bres; scatter bucket-streamed. No global scan kernel.
// ============================================================
__global__ __launch_bounds__(256) void k_bin(
    const int* __restrict__ ei, const int* __restrict__ btot,
    int* __restrict__ bres, int* __restrict__ binned, int E, int chunk)
{
    __shared__ int h[NB];
    __shared__ int base_s[NB];
    __shared__ int ws[4];
    int t = threadIdx.x;
    {
        int v0 = btot[2 * t], v1 = btot[2 * t + 1];
        int s = v0 + v1;
        int lane = t & 63, w = t >> 6;
        int x = s;
#pragma unroll
        for (int o = 1; o < 64; o <<= 1) {
            int y = __shfl_up(x, o);
            if (lane >= o) x += y;
        }
        if (lane == 63) ws[w] = x;
        __syncthreads();
        int wb = 0;
#pragma unroll
        for (int k = 0; k < 4; ++k) wb += (k < w) ? ws[k] : 0;
        int ex = wb + x - s;
        base_s[2 * t] = ex;
        base_s[2 * t + 1] = ex + v0;
    }
    h[t] = 0; h[t + 256] = 0;
    __syncthreads();
    int e0 = blockIdx.x * chunk;
    int e1 = min(e0 + chunk, E);
    for (int e = e0 + t; e < e1; e += 256)
        atomicAdd(&h[ei[E + e] >> BSH], 1);
    __syncthreads();
    int c0 = h[t], c1 = h[t + 256];
    int b0 = base_s[t]       + (c0 ? atomicAdd(&bres[t], c0) : 0);
    int b1 = base_s[t + 256] + (c1 ? atomicAdd(&bres[t + 256], c1) : 0);
    __syncthreads();
    h[t] = b0; h[t + 256] = b1;
    __syncthreads();
    for (int e = e0 + t; e < e1; e += 256) {
        int s = ei[e];
        int d = ei[E + e];
        int p = atomicAdd(&h[d >> BSH], 1);  // LDS atomic
        binned[p] = s | ((d & ((1 << BSH) - 1)) << 17);
    }
}

// ============================================================
// CSR: per-bucket counting sort (LDS), one node per thread.
// Segment base = reduction of btot[0..b-1].
// ============================================================
__global__ __launch_bounds__(256) void k_ph_csr(
    const int* __restrict__ binned, const int* __restrict__ btot,
    int* __restrict__ csr, int* __restrict__ off, int* __restrict__ deg,
    int N, int E)
{
    __shared__ int cnt[256], loff[256], sd[256];
    __shared__ int ws[4];
    int b = blockIdx.x;
    int lo = b << BSH;
    if (lo >= N) return;
    int t = threadIdx.x;
    int lane = t & 63, w = t >> 6;
    // seg = sum(btot[0..b-1])
    int partial = 0;
    for (int i = t; i < b; i += 256) partial += btot[i];
#pragma unroll
    for (int o = 1; o < 64; o <<= 1) partial += __shfl_xor(partial, o);
    if (lane == 0) ws[w] = partial;
    cnt[t] = 0;
    __syncthreads();
    int seg = ws[0] + ws[1] + ws[2] + ws[3];
    int len = btot[b];
    for (int i = t; i < len; i += 256)
        atomicAdd(&cnt[(unsigned)binned[seg + i] >> 17], 1);
    __syncthreads();
    int a = cnt[t];
    sd[t] = a;
    __syncthreads();
    for (int o = 1; o < 256; o <<= 1) {
        int x = (t >= o) ? sd[t - o] : 0;
        __syncthreads();
        sd[t] += x;
        __syncthreads();
    }
    int ex = sd[t] - a;
    loff[t] = ex;
    int n0 = lo + t;
    if (n0 < N) { off[n0] = seg + ex; deg[n0] = a; }
    __syncthreads();
    for (int i = t; i < len; i += 256) {
        int v = binned[seg + i];
        int p = atomicAdd(&loff[(unsigned)v >> 17], 1);  // LDS atomic
        csr[seg + p] = v & 0x1ffff;
    }
}

// ============================================================
// Fused gather + GEMM2 + bias + ReLU.
// 16 lanes per node, 4 nodes/wave, 16 nodes/block. Inner loop:
// pair-unrolled double-buffered quad pipeline (buf0/buf1, static
// indexing) -> quad q+1's loads issue before quad q is consumed,
// doubling outstanding misses/wave. Flush points identical to r7
// (after odd quads + chunk tail) -> numerics unchanged.
// ============================================================
__global__ __launch_bounds__(256) void k_gather_fused(
    const __half* __restrict__ Hh, const float* __restrict__ as_,
    const float* __restrict__ ad_, const int* __restrict__ off,
    const int* __restrict__ deg, const int* __restrict__ csr,
    const f16* __restrict__ LWt, const float* __restrict__ bias,
    float* __restrict__ Out, int N)
{
    __shared__ __align__(16) __half2 wh[16][68];
    __shared__ int srcs[16][16];
    __shared__ __align__(16) f16 pt[16][136];  // P-tile, stride-136
    int t = threadIdx.x;
    int wid = t >> 6, lane = t & 63;
    int sub = lane >> 4;      // node sub-slot 0..3 (also MFMA quad q)
    int li = lane & 15;       // channel group: channels li*8..+7 (also MFMA m)
    int hh = li >> 2;         // head of this channel group
    int slot = wid * 4 + sub;
    int gbase = blockIdx.x * 16;
    int n = gbase + slot;
    bool nvalid = n < N;
    int dg = nvalid ? deg[n] : 0;
    int base = nvalid ? off[n] : 0;
    float4 adn = nvalid ? *(const float4*)(ad_ + (size_t)n * 4)
                        : make_float4(0.f, 0.f, 0.f, 0.f);

    float s0 = 0.f, s1 = 0.f, s2 = 0.f, s3 = 0.f;
    float acc[8] = {0.f, 0.f, 0.f, 0.f, 0.f, 0.f, 0.f, 0.f};

    for (int c0 = 0; c0 < dg; c0 += 16) {
        int cnt = min(16, dg - c0);
        // weight phase: lane li handles edge c0+li (zero weight if pad)
        {
            int idx = c0 + li;
            int se = csr[base + min(idx, dg - 1)];
            float4 as = *(const float4*)(as_ + (size_t)se * 4);
            float e0 = as.x + adn.x, e1 = as.y + adn.y;
            float e2 = as.z + adn.z, e3 = as.w + adn.w;
            e0 = fmaxf(e0, 0.2f * e0); e1 = fmaxf(e1, 0.2f * e1);
            e2 = fmaxf(e2, 0.2f * e2); e3 = fmaxf(e3, 0.2f * e3);
            float x0 = __expf(e0), x1 = __expf(e1);
            float x2 = __expf(e2), x3 = __expf(e3);
            if (idx >= dg) { x0 = x1 = x2 = x3 = 0.f; }
            s0 += x0; s1 += x1; s2 += x2; s3 += x3;
            __half2 w4[4];
            w4[0] = __float2half2_rn(x0);
            w4[1] = __float2half2_rn(x1);
            w4[2] = __float2half2_rn(x2);
            w4[3] = __float2half2_rn(x3);
            *(float4*)&wh[slot][li * 4] = *(float4*)w4;
            srcs[slot][li] = se;
        }
        __asm__ volatile("s_waitcnt lgkmcnt(0)" ::: "memory");
        int quads = (cnt + 3) >> 2;
        __half2 ah[4];
        ah[0] = ah[1] = ah[2] = ah[3] = __float2half2_rn(0.f);
        float4 buf0[4], buf1[4];
        // preload quad 0
#pragma unroll
        for (int u = 0; u < 4; ++u) {
            int se = srcs[slot][u];
            buf0[u] = *(const float4*)(Hh + (size_t)se * 128 + li * 8);
        }
        for (int qq = 0; qq < quads; qq += 2) {
            // prefetch quad qq+1 (dummy re-read of quad 0 if none)
            int nq1 = (qq + 1 < quads) ? (qq + 1) : 0;
#pragma unroll
            for (int u = 0; u < 4; ++u) {
                int se = srcs[slot][nq1 * 4 + u];
                buf1[u] = *(const float4*)(Hh + (size_t)se * 128 + li * 8);
            }
            // compute quad qq from buf0
#pragma unroll
            for (int u = 0; u < 4; ++u) {
                __half2 w2 = wh[slot][(qq * 4 + u) * 4 + hh];
                __half2* ph = (__half2*)&buf0[u];
                ah[0] = __hfma2(ph[0], w2, ah[0]);
                ah[1] = __hfma2(ph[1], w2, ah[1]);
                ah[2] = __hfma2(ph[2], w2, ah[2]);
                ah[3] = __hfma2(ph[3], w2, ah[3]);
            }
            // prefetch quad qq+2 into buf0 (dummy if none)
            int nq2 = (qq + 2 < quads) ? (qq + 2) : 0;
#pragma unroll
            for (int u = 0; u < 4; ++u) {
                int se = srcs[slot][nq2 * 4 + u];
                buf0[u] = *(const float4*)(Hh + (size_t)se * 128 + li * 8);
            }
            // compute quad qq+1 from buf1 (if it exists)
            if (qq + 1 < quads) {
#pragma unroll
                for (int u = 0; u < 4; ++u) {
                    __half2 w2 = wh[slot][((qq + 1) * 4 + u) * 4 + hh];
                    __half2* ph = (__half2*)&buf1[u];
                    ah[0] = __hfma2(ph[0], w2, ah[0]);
                    ah[1] = __hfma2(ph[1], w2, ah[1]);
                    ah[2] = __hfma2(ph[2], w2, ah[2]);
                    ah[3] = __hfma2(ph[3], w2, ah[3]);
                }
            }
            // f32 flush every pair (same points as r7: after odd quads)
#pragma unroll
            for (int k = 0; k < 4; ++k) {
                float2 f = __half22float2(ah[k]);
                acc[2 * k] += f.x; acc[2 * k + 1] += f.y;
                ah[k] = __float2half2_rn(0.f);
            }
        }
        __asm__ volatile("s_waitcnt lgkmcnt(0)" ::: "memory");
    }

    // softmax denominators: reduce within the 16-lane node group
#pragma unroll
    for (int o = 1; o < 16; o <<= 1) {
        s0 += __shfl_xor(s0, o);
        s1 += __shfl_xor(s1, o);
        s2 += __shfl_xor(s2, o);
        s3 += __shfl_xor(s3, o);
    }
    float sh = (hh == 0) ? s0 : (hh == 1) ? s1 : (hh == 2) ? s2 : s3;
    float inv = 1.f / (sh + 1e-16f);
    {
        __half2 o4[4];
#pragma unroll
        for (int k = 0; k < 4; ++k)
            o4[k] = __float22half2_rn(make_float2(acc[2 * k] * inv, acc[2 * k + 1] * inv));
        *(float4*)&pt[slot][li * 8] = *(float4*)o4;  // invalid rows: acc==0 -> zeros
    }
    __syncthreads();

    // GEMM2 phase: Out[16 rows] = relu(pt @ lin_w + bias).
    {
        int cc = wid * 32;
        f32x4 acc2[2];
        acc2[0] = (f32x4){0.f, 0.f, 0.f, 0.f};
        acc2[1] = (f32x4){0.f, 0.f, 0.f, 0.f};
        const f16* wp = LWt + (size_t)(cc + li) * 128 + sub * 8;
#pragma unroll
        for (int ks = 0; ks < 4; ++ks) {
            half8 a0 = *(const half8*)&pt[li][ks * 32 + sub * 8];
            half8 b0 = *(const half8*)(wp + ks * 32);
            half8 b1 = *(const half8*)(wp + 16 * 128 + ks * 32);
            acc2[0] = __builtin_amdgcn_mfma_f32_16x16x32_f16(a0, b0, acc2[0], 0, 0, 0);
            acc2[1] = __builtin_amdgcn_mfma_f32_16x16x32_f16(a0, b1, acc2[1], 0, 0, 0);
        }
        float bv0 = bias[cc + li];
        float bv1 = bias[cc + 16 + li];
#pragma unroll
        for (int g = 0; g < 4; ++g) {
            int r = sub * 4 + g;
            int node = gbase + r;
            if (node < N) {
                Out[(size_t)node * 128 + cc + li]      = fmaxf(acc2[0][g] + bv0, 0.f);
                Out[(size_t)node * 128 + cc + 16 + li] = fmaxf(acc2[1][g] + bv1, 0.f);
            }
        }
    }
}

// ============================================================

extern "C" void kernel_launch(void* const* d_in, const int* in_sizes, int n_in,
                              void* d_out, int out_size, void* d_ws, size_t ws_size,
                              hipStream_t stream)
{
    const float* x     = (const float*)d_in[0];
    const int*   ei    = (const int*)d_in[1];
    const float* W     = (const float*)d_in[2];
    const float* att_s = (const float*)d_in[3];
    const float* att_d = (const float*)d_in[4];
    const float* lin_w = (const float*)d_in[5];
    const float* lin_b = (const float*)d_in[6];
    float* out = (float*)d_out;
    int N = in_sizes[0] / 128;
    int E = in_sizes[1] / 2;

    char* p = (char*)d_ws;
    auto alloc = [&](size_t bytes) { char* r = p; p += (bytes + 255) & ~(size_t)255; return r; };
    f16*    Hh   = (f16*)alloc((size_t)N * 128 * 2);
    f16*    Wt   = (f16*)alloc(128 * 128 * 2);
    f16*    LWt  = (f16*)alloc(128 * 128 * 2);
    float*  AS   = (float*)alloc((size_t)N * 4 * 4);
    float*  AD   = (float*)alloc((size_t)N * 4 * 4);
    int*    deg  = (int*)alloc((size_t)N * 4);
    int*    off  = (int*)alloc((size_t)N * 4);
    int*    btot = (int*)alloc((size_t)NB * 4 * 2);  // btot[NB] + bres[NB]
    int*    bres = btot + NB;
    int*    csr  = (int*)alloc((size_t)E * 4);
    int*    binned = (int*)alloc((size_t)E * 4);

    int hchunk = (E + HBLK - 1) / HBLK;
    int bchunk = (E + BBLK - 1) / BBLK;
    int mb = (N + 63) / 64;
    hipMemsetAsync(btot, 0, (size_t)NB * 4 * 2, stream);
    k_setup<<<128 + HBLK, 256, 0, stream>>>(W, lin_w, Wt, LWt, ei + E, btot, E, hchunk);
    k_gemm_att<<<mb, 256, 0, stream>>>(x, Wt, att_s, att_d, Hh, AS, AD, N);
    k_bin<<<BBLK, 256, 0, stream>>>(ei, btot, bres, binned, E, bchunk);
    k_ph_csr<<<NB, 256, 0, stream>>>(binned, btot, csr, off, deg, N, E);
    k_gather_fused<<<(N + 15) / 16, 256, 0, stream>>>(
        (const __half*)Hh, AS, AD, off, deg, csr, LWt, lin_b, out, N);
}

// Round 9
// 277.305 us; speedup vs baseline: 1.0286x; 1.0286x over previous
//
#include <hip/hip_runtime.h>
#include <hip/hip_fp16.h>

#define NB    512   // dst buckets (256 nodes each), bucket = dst >> 8
#define BSH   8
#define HBLK  384   // hist blocks in k_setup
#define BBLK  512   // blocks in k_bin

typedef _Float16 f16;
typedef _Float16 half8 __attribute__((ext_vector_type(8)));
typedef __fp16 pk16x2 __attribute__((ext_vector_type(2)));  // cvt_pkrtz return type
typedef float f32x4 __attribute__((ext_vector_type(4)));

// ============================================================
// Setup (fused): blocks 0..127 transpose W/lin_w -> Wt/LWt f16;
// blocks 128.. run the dst-bucket histogram, LDS-aggregated ->
// 512 global atomics per block into btot (pre-zeroed).
// ============================================================
__global__ __launch_bounds__(256) void k_setup(
    const float* __restrict__ W, const float* __restrict__ LW,
    f16* __restrict__ Wt, f16* __restrict__ LWt,
    const int* __restrict__ dst, int* __restrict__ btot, int E, int chunk)
{
    int b = blockIdx.x;
    int t = threadIdx.x;
    if (b < 128) {
        if (t < 128) Wt[b * 128 + t]           = (f16)W[t * 128 + b];
        else         LWt[b * 128 + (t - 128)]  = (f16)LW[(t - 128) * 128 + b];
        return;
    }
    __shared__ int h[NB];
    h[t] = 0; h[t + 256] = 0;
    __syncthreads();
    int blk = b - 128;
    int e0 = blk * chunk;
    int e1 = min(e0 + chunk, E);
    for (int e = e0 + t; e < e1; e += 256)
        atomicAdd(&h[dst[e] >> BSH], 1);
    __syncthreads();
    if (h[t])       atomicAdd(&btot[t], h[t]);
    if (h[t + 256]) atomicAdd(&btot[t + 256], h[t + 256]);
}

// ============================================================
// MFMA GEMM 1: H = x @ W + attention-logit epilogue. Tile 64x128.
// ============================================================
__global__ __launch_bounds__(256) void k_gemm_att(
    const float* __restrict__ A, const f16* __restrict__ Wt,
    const float* __restrict__ att_s, const float* __restrict__ att_d,
    f16* __restrict__ Hh, float* __restrict__ as_out, float* __restrict__ ad_out,
    int M)
{
    __shared__ __align__(16) f16 as_lds[64 * 136];
    int t = threadIdx.x;
    int row0 = blockIdx.x * 64;

    // Stage A: f32 -> f16 packed, [m][k] stride 136
    {
        int r = t >> 2, kq = (t & 3) * 32;
        const float* ap = A + (size_t)(row0 + r) * 128 + kq;
        bool valid = (row0 + r) < M;
        pk16x2 hb[16];
#pragma unroll
        for (int j = 0; j < 8; ++j) {
            float4 v = valid ? *(const float4*)(ap + j * 4) : make_float4(0.f, 0.f, 0.f, 0.f);
            hb[2 * j]     = __builtin_amdgcn_cvt_pkrtz(v.x, v.y);
            hb[2 * j + 1] = __builtin_amdgcn_cvt_pkrtz(v.z, v.w);
        }
        f16* dst = as_lds + r * 136 + kq;
#pragma unroll
        for (int j = 0; j < 4; ++j) *(float4*)(dst + j * 8) = ((float4*)hb)[j];
    }
    __syncthreads();

    int w = t >> 6, ln = t & 63;
    int rr = (w & 1) * 32;
    int cc = (w >> 1) * 64;
    int q = ln >> 4, m = ln & 15;

    f32x4 acc[2][4];
#pragma unroll
    for (int i = 0; i < 2; ++i)
#pragma unroll
        for (int j = 0; j < 4; ++j) acc[i][j] = (f32x4){0.f, 0.f, 0.f, 0.f};

    const f16* wp = Wt + (size_t)(cc + m) * 128 + q * 8;
#pragma unroll
    for (int ks = 0; ks < 4; ++ks) {
        int k0 = ks * 32 + q * 8;
        half8 a0 = *(const half8*)(as_lds + (rr + m) * 136 + k0);
        half8 a1 = *(const half8*)(as_lds + (rr + 16 + m) * 136 + k0);
        half8 bf[4];
#pragma unroll
        for (int j = 0; j < 4; ++j)
            bf[j] = *(const half8*)(wp + j * 16 * 128 + ks * 32);
#pragma unroll
        for (int j = 0; j < 4; ++j) {
            acc[0][j] = __builtin_amdgcn_mfma_f32_16x16x32_f16(a0, bf[j], acc[0][j], 0, 0, 0);
            acc[1][j] = __builtin_amdgcn_mfma_f32_16x16x32_f16(a1, bf[j], acc[1][j], 0, 0, 0);
        }
    }
    __syncthreads();
#pragma unroll
    for (int i = 0; i < 2; ++i)
#pragma unroll
        for (int j = 0; j < 4; ++j)
#pragma unroll
            for (int g = 0; g < 4; ++g)
                as_lds[(rr + i * 16 + q * 4 + g) * 136 + cc + j * 16 + m] = (f16)acc[i][j][g];
    __syncthreads();
    // coalesced H write
    {
        int r = t >> 2, cq = (t & 3) * 32;
        if (row0 + r < M) {
            float4 o0 = *(const float4*)(as_lds + r * 136 + cq);
            float4 o1 = *(const float4*)(as_lds + r * 136 + cq + 8);
            float4 o2 = *(const float4*)(as_lds + r * 136 + cq + 16);
            float4 o3 = *(const float4*)(as_lds + r * 136 + cq + 24);
            float4* hp = (float4*)(Hh + (size_t)(row0 + r) * 128 + cq);
            hp[0] = o0; hp[1] = o1; hp[2] = o2; hp[3] = o3;
        }
    }
    // attention dots
    {
        int rl = w * 16 + m;
        int head = q;
        float ds = 0.f, dd = 0.f;
#pragma unroll
        for (int ch = 0; ch < 4; ++ch) {
            half8 hv = *(const half8*)(as_lds + rl * 136 + head * 32 + ch * 8);
            float4 s0 = *(const float4*)(att_s + head * 32 + ch * 8);
            float4 s1 = *(const float4*)(att_s + head * 32 + ch * 8 + 4);
            float4 d0 = *(const float4*)(att_d + head * 32 + ch * 8);
            float4 d1 = *(const float4*)(att_d + head * 32 + ch * 8 + 4);
            ds += (float)hv[0] * s0.x + (float)hv[1] * s0.y + (float)hv[2] * s0.z + (float)hv[3] * s0.w
                + (float)hv[4] * s1.x + (float)hv[5] * s1.y + (float)hv[6] * s1.z + (float)hv[7] * s1.w;
            dd += (float)hv[0] * d0.x + (float)hv[1] * d0.y + (float)hv[2] * d0.z + (float)hv[3] * d0.w
                + (float)hv[4] * d1.x + (float)hv[5] * d1.y + (float)hv[6] * d1.z + (float)hv[7] * d1.w;
        }
        if (row0 + rl < M) {
            as_out[(row0 + rl) * 4 + head] = ds;
            ad_out[(row0 + rl) * 4 + head] = dd;
        }
    }
}

// ============================================================
// Bin: bucket scatter with per-block range reservation.
// Local exclusive scan of btot (512 entries, 2/thread) -> bases;
// LDS hist of chunk; reserve per-bucket ranges via atomicAdd on
// bres; scatter bucket-streamed. No global scan kernel.
// ============================================================
__global__ __launch_bounds__(256) void k_bin(
    const int* __restrict__ ei, const int* __restrict__ btot,
    int* __restrict__ bres, int* __restrict__ binned, int E, int chunk)
{
    __shared__ int h[NB];
    __shared__ int base_s[NB];
    __shared__ int ws[4];
    int t = threadIdx.x;
    {
        int v0 = btot[2 * t], v1 = btot[2 * t + 1];
        int s = v0 + v1;
        int lane = t & 63, w = t >> 6;
        int x = s;
#pragma unroll
        for (int o = 1; o < 64; o <<= 1) {
            int y = __shfl_up(x, o);
            if (lane >= o) x += y;
        }
        if (lane == 63) ws[w] = x;
        __syncthreads();
        int wb = 0;
#pragma unroll
        for (int k = 0; k < 4; ++k) wb += (k < w) ? ws[k] : 0;
        int ex = wb + x - s;
        base_s[2 * t] = ex;
        base_s[2 * t + 1] = ex + v0;
    }
    h[t] = 0; h[t + 256] = 0;
    __syncthreads();
    int e0 = blockIdx.x * chunk;
    int e1 = min(e0 + chunk, E);
    for (int e = e0 + t; e < e1; e += 256)
        atomicAdd(&h[ei[E + e] >> BSH], 1);
    __syncthreads();
    int c0 = h[t], c1 = h[t + 256];
    int b0 = base_s[t]       + (c0 ? atomicAdd(&bres[t], c0) : 0);
    int b1 = base_s[t + 256] + (c1 ? atomicAdd(&bres[t + 256], c1) : 0);
    __syncthreads();
    h[t] = b0; h[t + 256] = b1;
    __syncthreads();
    for (int e = e0 + t; e < e1; e += 256) {
        int s = ei[e];
        int d = ei[E + e];
        int p = atomicAdd(&h[d >> BSH], 1);  // LDS atomic
        binned[p] = s | ((d & ((1 << BSH) - 1)) << 17);
    }
}

// ============================================================
// CSR: per-bucket counting sort (LDS), one node per thread.
// Segment base = reduction of btot[0..b-1].
// ============================================================
__global__ __launch_bounds__(256) void k_ph_csr(
    const int* __restrict__ binned, const int* __restrict__ btot,
    int* __restrict__ csr, int* __restrict__ off, int* __restrict__ deg,
    int N, int E)
{
    __shared__ int cnt[256], loff[256], sd[256];
    __shared__ int ws[4];
    int b = blockIdx.x;
    int lo = b << BSH;
    if (lo >= N) return;
    int t = threadIdx.x;
    int lane = t & 63, w = t >> 6;
    // seg = sum(btot[0..b-1])
    int partial = 0;
    for (int i = t; i < b; i += 256) partial += btot[i];
#pragma unroll
    for (int o = 1; o < 64; o <<= 1) partial += __shfl_xor(partial, o);
    if (lane == 0) ws[w] = partial;
    cnt[t] = 0;
    __syncthreads();
    int seg = ws[0] + ws[1] + ws[2] + ws[3];
    int len = btot[b];
    for (int i = t; i < len; i += 256)
        atomicAdd(&cnt[(unsigned)binned[seg + i] >> 17], 1);
    __syncthreads();
    int a = cnt[t];
    sd[t] = a;
    __syncthreads();
    for (int o = 1; o < 256; o <<= 1) {
        int x = (t >= o) ? sd[t - o] : 0;
        __syncthreads();
        sd[t] += x;
        __syncthreads();
    }
    int ex = sd[t] - a;
    loff[t] = ex;
    int n0 = lo + t;
    if (n0 < N) { off[n0] = seg + ex; deg[n0] = a; }
    __syncthreads();
    for (int i = t; i < len; i += 256) {
        int v = binned[seg + i];
        int p = atomicAdd(&loff[(unsigned)v >> 17], 1);  // LDS atomic
        csr[seg + p] = v & 0x1ffff;
    }
}

// ============================================================
// Fused gather + GEMM2 + bias + ReLU (r7-proven inner loop).
// 16 lanes per node, 4 nodes/wave, 16 nodes/block. __hfma2
// accumulate, f32 flush every 8 edges. After gather the block
// holds a 16x128 P-tile in LDS -> 16x128 @ 128x128 MFMA epilogue.
// ============================================================
__global__ __launch_bounds__(256) void k_gather_fused(
    const __half* __restrict__ Hh, const float* __restrict__ as_,
    const float* __restrict__ ad_, const int* __restrict__ off,
    const int* __restrict__ deg, const int* __restrict__ csr,
    const f16* __restrict__ LWt, const float* __restrict__ bias,
    float* __restrict__ Out, int N)
{
    __shared__ __align__(16) __half2 wh[16][68];
    __shared__ int srcs[16][16];
    __shared__ __align__(16) f16 pt[16][136];  // P-tile, stride-136
    int t = threadIdx.x;
    int wid = t >> 6, lane = t & 63;
    int sub = lane >> 4;      // node sub-slot 0..3 (also MFMA quad q)
    int li = lane & 15;       // channel group: channels li*8..+7 (also MFMA m)
    int hh = li >> 2;         // head of this channel group
    int slot = wid * 4 + sub;
    int gbase = blockIdx.x * 16;
    int n = gbase + slot;
    bool nvalid = n < N;
    int dg = nvalid ? deg[n] : 0;
    int base = nvalid ? off[n] : 0;
    float4 adn = nvalid ? *(const float4*)(ad_ + (size_t)n * 4)
                        : make_float4(0.f, 0.f, 0.f, 0.f);

    float s0 = 0.f, s1 = 0.f, s2 = 0.f, s3 = 0.f;
    float acc[8] = {0.f, 0.f, 0.f, 0.f, 0.f, 0.f, 0.f, 0.f};

    for (int c0 = 0; c0 < dg; c0 += 16) {
        int cnt = min(16, dg - c0);
        // weight phase: lane li handles edge c0+li (zero weight if pad)
        {
            int idx = c0 + li;
            int se = csr[base + min(idx, dg - 1)];
            float4 as = *(const float4*)(as_ + (size_t)se * 4);
            float e0 = as.x + adn.x, e1 = as.y + adn.y;
            float e2 = as.z + adn.z, e3 = as.w + adn.w;
            e0 = fmaxf(e0, 0.2f * e0); e1 = fmaxf(e1, 0.2f * e1);
            e2 = fmaxf(e2, 0.2f * e2); e3 = fmaxf(e3, 0.2f * e3);
            float x0 = __expf(e0), x1 = __expf(e1);
            float x2 = __expf(e2), x3 = __expf(e3);
            if (idx >= dg) { x0 = x1 = x2 = x3 = 0.f; }
            s0 += x0; s1 += x1; s2 += x2; s3 += x3;
            __half2 w4[4];
            w4[0] = __float2half2_rn(x0);
            w4[1] = __float2half2_rn(x1);
            w4[2] = __float2half2_rn(x2);
            w4[3] = __float2half2_rn(x3);
            *(float4*)&wh[slot][li * 4] = *(float4*)w4;
            srcs[slot][li] = se;
        }
        __asm__ volatile("s_waitcnt lgkmcnt(0)" ::: "memory");
        // main loop: 4-edge quads, pad edges carry zero weight
        int quads = (cnt + 3) >> 2;
        __half2 ah[4];
        ah[0] = ah[1] = ah[2] = ah[3] = __float2half2_rn(0.f);
        for (int qq = 0; qq < quads; ++qq) {
#pragma unroll
            for (int u = 0; u < 4; ++u) {
                int i = qq * 4 + u;
                __half2 w2 = wh[slot][i * 4 + hh];
                int se = srcs[slot][i];
                float4 raw = *(const float4*)(Hh + (size_t)se * 128 + li * 8);
                __half2* ph = (__half2*)&raw;
                ah[0] = __hfma2(ph[0], w2, ah[0]);
                ah[1] = __hfma2(ph[1], w2, ah[1]);
                ah[2] = __hfma2(ph[2], w2, ah[2]);
                ah[3] = __hfma2(ph[3], w2, ah[3]);
            }
            if ((qq & 1) == 1) {  // f32 flush every 8 edges
#pragma unroll
                for (int k = 0; k < 4; ++k) {
                    float2 f = __half22float2(ah[k]);
                    acc[2 * k] += f.x; acc[2 * k + 1] += f.y;
                    ah[k] = __float2half2_rn(0.f);
                }
            }
        }
#pragma unroll
        for (int k = 0; k < 4; ++k) {  // tail flush (chunk end)
            float2 f = __half22float2(ah[k]);
            acc[2 * k] += f.x; acc[2 * k + 1] += f.y;
        }
        __asm__ volatile("s_waitcnt lgkmcnt(0)" ::: "memory");
    }

    // softmax denominators: reduce within the 16-lane node group
#pragma unroll
    for (int o = 1; o < 16; o <<= 1) {
        s0 += __shfl_xor(s0, o);
        s1 += __shfl_xor(s1, o);
        s2 += __shfl_xor(s2, o);
        s3 += __shfl_xor(s3, o);
    }
    float sh = (hh == 0) ? s0 : (hh == 1) ? s1 : (hh == 2) ? s2 : s3;
    float inv = 1.f / (sh + 1e-16f);
    {
        __half2 o4[4];
#pragma unroll
        for (int k = 0; k < 4; ++k)
            o4[k] = __float22half2_rn(make_float2(acc[2 * k] * inv, acc[2 * k + 1] * inv));
        *(float4*)&pt[slot][li * 8] = *(float4*)o4;  // invalid rows: acc==0 -> zeros
    }
    __syncthreads();

    // GEMM2 phase: Out[16 rows] = relu(pt @ lin_w + bias).
    // Wave wid owns cols cc..cc+31. A[m=li][k=sub*8+j] from pt;
    // B from LWt [n][k]; C/D col=li row=sub*4+g.
    {
        int cc = wid * 32;
        f32x4 acc2[2];
        acc2[0] = (f32x4){0.f, 0.f, 0.f, 0.f};
        acc2[1] = (f32x4){0.f, 0.f, 0.f, 0.f};
        const f16* wp = LWt + (size_t)(cc + li) * 128 + sub * 8;
#pragma unroll
        for (int ks = 0; ks < 4; ++ks) {
            half8 a0 = *(const half8*)&pt[li][ks * 32 + sub * 8];
            half8 b0 = *(const half8*)(wp + ks * 32);
            half8 b1 = *(const half8*)(wp + 16 * 128 + ks * 32);
            acc2[0] = __builtin_amdgcn_mfma_f32_16x16x32_f16(a0, b0, acc2[0], 0, 0, 0);
            acc2[1] = __builtin_amdgcn_mfma_f32_16x16x32_f16(a0, b1, acc2[1], 0, 0, 0);
        }
        float bv0 = bias[cc + li];
        float bv1 = bias[cc + 16 + li];
#pragma unroll
        for (int g = 0; g < 4; ++g) {
            int r = sub * 4 + g;
            int node = gbase + r;
            if (node < N) {
                Out[(size_t)node * 128 + cc + li]      = fmaxf(acc2[0][g] + bv0, 0.f);
                Out[(size_t)node * 128 + cc + 16 + li] = fmaxf(acc2[1][g] + bv1, 0.f);
            }
        }
    }
}

// ============================================================

extern "C" void kernel_launch(void* const* d_in, const int* in_sizes, int n_in,
                              void* d_out, int out_size, void* d_ws, size_t ws_size,
                              hipStream_t stream)
{
    const float* x     = (const float*)d_in[0];
    const int*   ei    = (const int*)d_in[1];
    const float* W     = (const float*)d_in[2];
    const float* att_s = (const float*)d_in[3];
    const float* att_d = (const float*)d_in[4];
    const float* lin_w = (const float*)d_in[5];
    const float* lin_b = (const float*)d_in[6];
    float* out = (float*)d_out;
    int N = in_sizes[0] / 128;
    int E = in_sizes[1] / 2;

    char* p = (char*)d_ws;
    auto alloc = [&](size_t bytes) { char* r = p; p += (bytes + 255) & ~(size_t)255; return r; };
    f16*    Hh   = (f16*)alloc((size_t)N * 128 * 2);
    f16*    Wt   = (f16*)alloc(128 * 128 * 2);
    f16*    LWt  = (f16*)alloc(128 * 128 * 2);
    float*  AS   = (float*)alloc((size_t)N * 4 * 4);
    float*  AD   = (float*)alloc((size_t)N * 4 * 4);
    int*    deg  = (int*)alloc((size_t)N * 4);
    int*    off  = (int*)alloc((size_t)N * 4);
    int*    btot = (int*)alloc((size_t)NB * 4 * 2);  // btot[NB] + bres[NB]
    int*    bres = btot + NB;
    int*    csr  = (int*)alloc((size_t)E * 4);
    int*    binned = (int*)alloc((size_t)E * 4);

    int hchunk = (E + HBLK - 1) / HBLK;
    int bchunk = (E + BBLK - 1) / BBLK;
    int mb = (N + 63) / 64;
    hipMemsetAsync(btot, 0, (size_t)NB * 4 * 2, stream);
    k_setup<<<128 + HBLK, 256, 0, stream>>>(W, lin_w, Wt, LWt, ei + E, btot, E, hchunk);
    k_gemm_att<<<mb, 256, 0, stream>>>(x, Wt, att_s, att_d, Hh, AS, AD, N);
    k_bin<<<BBLK, 256, 0, stream>>>(ei, btot, bres, binned, E, bchunk);
    k_ph_csr<<<NB, 256, 0, stream>>>(binned, btot, csr, off, deg, N, E);
    k_gather_fused<<<(N + 15) / 16, 256, 0, stream>>>(
        (const __half*)Hh, AS, AD, off, deg, csr, LWt, lin_b, out, N);
}

// Round 10
// 271.703 us; speedup vs baseline: 1.0498x; 1.0206x over previous
//
#include <hip/hip_runtime.h>
#include <hip/hip_fp16.h>

#define NB    512   // dst buckets (256 nodes each), bucket = dst >> 8
#define BSH   8
#define HBLK  384   // hist blocks in k_setup
#define BBLK  512   // bin blocks in k_gemm_bin

typedef _Float16 f16;
typedef _Float16 half8 __attribute__((ext_vector_type(8)));
typedef __fp16 pk16x2 __attribute__((ext_vector_type(2)));  // cvt_pkrtz return type
typedef float f32x4 __attribute__((ext_vector_type(4)));

// ============================================================
// Setup (fused): blocks 0..127 transpose W/lin_w -> Wt/LWt f16;
// blocks 128.. run the dst-bucket histogram, LDS-aggregated ->
// 512 global atomics per block into btot (pre-zeroed).
// ============================================================
__global__ __launch_bounds__(256) void k_setup(
    const float* __restrict__ W, const float* __restrict__ LW,
    f16* __restrict__ Wt, f16* __restrict__ LWt,
    const int* __restrict__ dst, int* __restrict__ btot, int E, int chunk)
{
    int b = blockIdx.x;
    int t = threadIdx.x;
    if (b < 128) {
        if (t < 128) Wt[b * 128 + t]           = (f16)W[t * 128 + b];
        else         LWt[b * 128 + (t - 128)]  = (f16)LW[(t - 128) * 128 + b];
        return;
    }
    __shared__ int h[NB];
    h[t] = 0; h[t + 256] = 0;
    __syncthreads();
    int blk = b - 128;
    int e0 = blk * chunk;
    int e1 = min(e0 + chunk, E);
    for (int e = e0 + t; e < e1; e += 256)
        atomicAdd(&h[dst[e] >> BSH], 1);
    __syncthreads();
    if (h[t])       atomicAdd(&btot[t], h[t]);
    if (h[t + 256]) atomicAdd(&btot[t + 256], h[t + 256]);
}

// ============================================================
// Mega-kernel: blocks [0, mb) = MFMA GEMM 1 (H = x @ W + attention
// logits); blocks [mb, mb+BBLK) = bucket bin scatter. The two are
// dataflow-independent (both need only k_setup's outputs) and have
// complementary resource profiles (MFMA/VALU vs memory/atomic) ->
// co-residency overlaps them and saves a launch.
// ============================================================
__global__ __launch_bounds__(256) void k_gemm_bin(
    // gemm args
    const float* __restrict__ A, const f16* __restrict__ Wt,
    const float* __restrict__ att_s, const float* __restrict__ att_d,
    f16* __restrict__ Hh, float* __restrict__ as_out, float* __restrict__ ad_out,
    int M, int mb,
    // bin args
    const int* __restrict__ ei, const int* __restrict__ btot,
    int* __restrict__ bres, int* __restrict__ binned, int E, int chunk)
{
    int t = threadIdx.x;
    if (blockIdx.x >= mb) {
        // ---------------- bin path ----------------
        __shared__ int h[NB];
        __shared__ int base_s[NB];
        __shared__ int ws[4];
        {
            int v0 = btot[2 * t], v1 = btot[2 * t + 1];
            int s = v0 + v1;
            int lane = t & 63, w = t >> 6;
            int x = s;
#pragma unroll
            for (int o = 1; o < 64; o <<= 1) {
                int y = __shfl_up(x, o);
                if (lane >= o) x += y;
            }
            if (lane == 63) ws[w] = x;
            __syncthreads();
            int wb = 0;
#pragma unroll
            for (int k = 0; k < 4; ++k) wb += (k < w) ? ws[k] : 0;
            int ex = wb + x - s;
            base_s[2 * t] = ex;
            base_s[2 * t + 1] = ex + v0;
        }
        h[t] = 0; h[t + 256] = 0;
        __syncthreads();
        int blk = blockIdx.x - mb;
        int e0 = blk * chunk;
        int e1 = min(e0 + chunk, E);
        for (int e = e0 + t; e < e1; e += 256)
            atomicAdd(&h[ei[E + e] >> BSH], 1);
        __syncthreads();
        int c0 = h[t], c1 = h[t + 256];
        int b0 = base_s[t]       + (c0 ? atomicAdd(&bres[t], c0) : 0);
        int b1 = base_s[t + 256] + (c1 ? atomicAdd(&bres[t + 256], c1) : 0);
        __syncthreads();
        h[t] = b0; h[t + 256] = b1;
        __syncthreads();
        for (int e = e0 + t; e < e1; e += 256) {
            int s = ei[e];
            int d = ei[E + e];
            int p = atomicAdd(&h[d >> BSH], 1);  // LDS atomic
            binned[p] = s | ((d & ((1 << BSH) - 1)) << 17);
        }
        return;
    }
    // ---------------- gemm path ----------------
    __shared__ __align__(16) f16 as_lds[64 * 136];
    int row0 = blockIdx.x * 64;

    // Stage A: f32 -> f16 packed, [m][k] stride 136
    {
        int r = t >> 2, kq = (t & 3) * 32;
        const float* ap = A + (size_t)(row0 + r) * 128 + kq;
        bool valid = (row0 + r) < M;
        pk16x2 hb[16];
#pragma unroll
        for (int j = 0; j < 8; ++j) {
            float4 v = valid ? *(const float4*)(ap + j * 4) : make_float4(0.f, 0.f, 0.f, 0.f);
            hb[2 * j]     = __builtin_amdgcn_cvt_pkrtz(v.x, v.y);
            hb[2 * j + 1] = __builtin_amdgcn_cvt_pkrtz(v.z, v.w);
        }
        f16* dst = as_lds + r * 136 + kq;
#pragma unroll
        for (int j = 0; j < 4; ++j) *(float4*)(dst + j * 8) = ((float4*)hb)[j];
    }
    __syncthreads();

    int w = t >> 6, ln = t & 63;
    int rr = (w & 1) * 32;
    int cc = (w >> 1) * 64;
    int q = ln >> 4, m = ln & 15;

    f32x4 acc[2][4];
#pragma unroll
    for (int i = 0; i < 2; ++i)
#pragma unroll
        for (int j = 0; j < 4; ++j) acc[i][j] = (f32x4){0.f, 0.f, 0.f, 0.f};

    const f16* wp = Wt + (size_t)(cc + m) * 128 + q * 8;
#pragma unroll
    for (int ks = 0; ks < 4; ++ks) {
        int k0 = ks * 32 + q * 8;
        half8 a0 = *(const half8*)(as_lds + (rr + m) * 136 + k0);
        half8 a1 = *(const half8*)(as_lds + (rr + 16 + m) * 136 + k0);
        half8 bf[4];
#pragma unroll
        for (int j = 0; j < 4; ++j)
            bf[j] = *(const half8*)(wp + j * 16 * 128 + ks * 32);
#pragma unroll
        for (int j = 0; j < 4; ++j) {
            acc[0][j] = __builtin_amdgcn_mfma_f32_16x16x32_f16(a0, bf[j], acc[0][j], 0, 0, 0);
            acc[1][j] = __builtin_amdgcn_mfma_f32_16x16x32_f16(a1, bf[j], acc[1][j], 0, 0, 0);
        }
    }
    __syncthreads();
#pragma unroll
    for (int i = 0; i < 2; ++i)
#pragma unroll
        for (int j = 0; j < 4; ++j)
#pragma unroll
            for (int g = 0; g < 4; ++g)
                as_lds[(rr + i * 16 + q * 4 + g) * 136 + cc + j * 16 + m] = (f16)acc[i][j][g];
    __syncthreads();
    // coalesced H write
    {
        int r = t >> 2, cq = (t & 3) * 32;
        if (row0 + r < M) {
            float4 o0 = *(const float4*)(as_lds + r * 136 + cq);
            float4 o1 = *(const float4*)(as_lds + r * 136 + cq + 8);
            float4 o2 = *(const float4*)(as_lds + r * 136 + cq + 16);
            float4 o3 = *(const float4*)(as_lds + r * 136 + cq + 24);
            float4* hp = (float4*)(Hh + (size_t)(row0 + r) * 128 + cq);
            hp[0] = o0; hp[1] = o1; hp[2] = o2; hp[3] = o3;
        }
    }
    // attention dots
    {
        int rl = w * 16 + m;
        int head = q;
        float ds = 0.f, dd = 0.f;
#pragma unroll
        for (int ch = 0; ch < 4; ++ch) {
            half8 hv = *(const half8*)(as_lds + rl * 136 + head * 32 + ch * 8);
            float4 s0 = *(const float4*)(att_s + head * 32 + ch * 8);
            float4 s1 = *(const float4*)(att_s + head * 32 + ch * 8 + 4);
            float4 d0 = *(const float4*)(att_d + head * 32 + ch * 8);
            float4 d1 = *(const float4*)(att_d + head * 32 + ch * 8 + 4);
            ds += (float)hv[0] * s0.x + (float)hv[1] * s0.y + (float)hv[2] * s0.z + (float)hv[3] * s0.w
                + (float)hv[4] * s1.x + (float)hv[5] * s1.y + (float)hv[6] * s1.z + (float)hv[7] * s1.w;
            dd += (float)hv[0] * d0.x + (float)hv[1] * d0.y + (float)hv[2] * d0.z + (float)hv[3] * d0.w
                + (float)hv[4] * d1.x + (float)hv[5] * d1.y + (float)hv[6] * d1.z + (float)hv[7] * d1.w;
        }
        if (row0 + rl < M) {
            as_out[(row0 + rl) * 4 + head] = ds;
            ad_out[(row0 + rl) * 4 + head] = dd;
        }
    }
}

// ============================================================
// CSR: per-bucket counting sort (LDS), one node per thread.
// Segment base = reduction of btot[0..b-1].
// ============================================================
__global__ __launch_bounds__(256) void k_ph_csr(
    const int* __restrict__ binned, const int* __restrict__ btot,
    int* __restrict__ csr, int* __restrict__ off, int* __restrict__ deg,
    int N, int E)
{
    __shared__ int cnt[256], loff[256], sd[256];
    __shared__ int ws[4];
    int b = blockIdx.x;
    int lo = b << BSH;
    if (lo >= N) return;
    int t = threadIdx.x;
    int lane = t & 63, w = t >> 6;
    // seg = sum(btot[0..b-1])
    int partial = 0;
    for (int i = t; i < b; i += 256) partial += btot[i];
#pragma unroll
    for (int o = 1; o < 64; o <<= 1) partial += __shfl_xor(partial, o);
    if (lane == 0) ws[w] = partial;
    cnt[t] = 0;
    __syncthreads();
    int seg = ws[0] + ws[1] + ws[2] + ws[3];
    int len = btot[b];
    for (int i = t; i < len; i += 256)
        atomicAdd(&cnt[(unsigned)binned[seg + i] >> 17], 1);
    __syncthreads();
    int a = cnt[t];
    sd[t] = a;
    __syncthreads();
    for (int o = 1; o < 256; o <<= 1) {
        int x = (t >= o) ? sd[t - o] : 0;
        __syncthreads();
        sd[t] += x;
        __syncthreads();
    }
    int ex = sd[t] - a;
    loff[t] = ex;
    int n0 = lo + t;
    if (n0 < N) { off[n0] = seg + ex; deg[n0] = a; }
    __syncthreads();
    for (int i = t; i < len; i += 256) {
        int v = binned[seg + i];
        int p = atomicAdd(&loff[(unsigned)v >> 17], 1);  // LDS atomic
        csr[seg + p] = v & 0x1ffff;
    }
}

// ============================================================
// Fused gather + GEMM2 + bias + ReLU (r7-proven inner loop).
// 16 lanes per node, 4 nodes/wave, 16 nodes/block. __hfma2
// accumulate, f32 flush every 8 edges. After gather the block
// holds a 16x128 P-tile in LDS -> 16x128 @ 128x128 MFMA epilogue.
// ============================================================
__global__ __launch_bounds__(256) void k_gather_fused(
    const __half* __restrict__ Hh, const float* __restrict__ as_,
    const float* __restrict__ ad_, const int* __restrict__ off,
    const int* __restrict__ deg, const int* __restrict__ csr,
    const f16* __restrict__ LWt, const float* __restrict__ bias,
    float* __restrict__ Out, int N)
{
    __shared__ __align__(16) __half2 wh[16][68];
    __shared__ int srcs[16][16];
    __shared__ __align__(16) f16 pt[16][136];  // P-tile, stride-136
    int t = threadIdx.x;
    int wid = t >> 6, lane = t & 63;
    int sub = lane >> 4;      // node sub-slot 0..3 (also MFMA quad q)
    int li = lane & 15;       // channel group: channels li*8..+7 (also MFMA m)
    int hh = li >> 2;         // head of this channel group
    int slot = wid * 4 + sub;
    int gbase = blockIdx.x * 16;
    int n = gbase + slot;
    bool nvalid = n < N;
    int dg = nvalid ? deg[n] : 0;
    int base = nvalid ? off[n] : 0;
    float4 adn = nvalid ? *(const float4*)(ad_ + (size_t)n * 4)
                        : make_float4(0.f, 0.f, 0.f, 0.f);

    float s0 = 0.f, s1 = 0.f, s2 = 0.f, s3 = 0.f;
    float acc[8] = {0.f, 0.f, 0.f, 0.f, 0.f, 0.f, 0.f, 0.f};

    for (int c0 = 0; c0 < dg; c0 += 16) {
        int cnt = min(16, dg - c0);
        // weight phase: lane li handles edge c0+li (zero weight if pad)
        {
            int idx = c0 + li;
            int se = csr[base + min(idx, dg - 1)];
            float4 as = *(const float4*)(as_ + (size_t)se * 4);
            float e0 = as.x + adn.x, e1 = as.y + adn.y;
            float e2 = as.z + adn.z, e3 = as.w + adn.w;
            e0 = fmaxf(e0, 0.2f * e0); e1 = fmaxf(e1, 0.2f * e1);
            e2 = fmaxf(e2, 0.2f * e2); e3 = fmaxf(e3, 0.2f * e3);
            float x0 = __expf(e0), x1 = __expf(e1);
            float x2 = __expf(e2), x3 = __expf(e3);
            if (idx >= dg) { x0 = x1 = x2 = x3 = 0.f; }
            s0 += x0; s1 += x1; s2 += x2; s3 += x3;
            __half2 w4[4];
            w4[0] = __float2half2_rn(x0);
            w4[1] = __float2half2_rn(x1);
            w4[2] = __float2half2_rn(x2);
            w4[3] = __float2half2_rn(x3);
            *(float4*)&wh[slot][li * 4] = *(float4*)w4;
            srcs[slot][li] = se;
        }
        __asm__ volatile("s_waitcnt lgkmcnt(0)" ::: "memory");
        // main loop: 4-edge quads, pad edges carry zero weight
        int quads = (cnt + 3) >> 2;
        __half2 ah[4];
        ah[0] = ah[1] = ah[2] = ah[3] = __float2half2_rn(0.f);
        for (int qq = 0; qq < quads; ++qq) {
#pragma unroll
            for (int u = 0; u < 4; ++u) {
                int i = qq * 4 + u;
                __half2 w2 = wh[slot][i * 4 + hh];
                int se = srcs[slot][i];
                float4 raw = *(const float4*)(Hh + (size_t)se * 128 + li * 8);
                __half2* ph = (__half2*)&raw;
                ah[0] = __hfma2(ph[0], w2, ah[0]);
                ah[1] = __hfma2(ph[1], w2, ah[1]);
                ah[2] = __hfma2(ph[2], w2, ah[2]);
                ah[3] = __hfma2(ph[3], w2, ah[3]);
            }
            if ((qq & 1) == 1) {  // f32 flush every 8 edges
#pragma unroll
                for (int k = 0; k < 4; ++k) {
                    float2 f = __half22float2(ah[k]);
                    acc[2 * k] += f.x; acc[2 * k + 1] += f.y;
                    ah[k] = __float2half2_rn(0.f);
                }
            }
        }
#pragma unroll
        for (int k = 0; k < 4; ++k) {  // tail flush (chunk end)
            float2 f = __half22float2(ah[k]);
            acc[2 * k] += f.x; acc[2 * k + 1] += f.y;
        }
        __asm__ volatile("s_waitcnt lgkmcnt(0)" ::: "memory");
    }

    // softmax denominators: reduce within the 16-lane node group
#pragma unroll
    for (int o = 1; o < 16; o <<= 1) {
        s0 += __shfl_xor(s0, o);
        s1 += __shfl_xor(s1, o);
        s2 += __shfl_xor(s2, o);
        s3 += __shfl_xor(s3, o);
    }
    float sh = (hh == 0) ? s0 : (hh == 1) ? s1 : (hh == 2) ? s2 : s3;
    float inv = 1.f / (sh + 1e-16f);
    {
        __half2 o4[4];
#pragma unroll
        for (int k = 0; k < 4; ++k)
            o4[k] = __float22half2_rn(make_float2(acc[2 * k] * inv, acc[2 * k + 1] * inv));
        *(float4*)&pt[slot][li * 8] = *(float4*)o4;  // invalid rows: acc==0 -> zeros
    }
    __syncthreads();

    // GEMM2 phase: Out[16 rows] = relu(pt @ lin_w + bias).
    // Wave wid owns cols cc..cc+31. A[m=li][k=sub*8+j] from pt;
    // B from LWt [n][k]; C/D col=li row=sub*4+g.
    {
        int cc = wid * 32;
        f32x4 acc2[2];
        acc2[0] = (f32x4){0.f, 0.f, 0.f, 0.f};
        acc2[1] = (f32x4){0.f, 0.f, 0.f, 0.f};
        const f16* wp = LWt + (size_t)(cc + li) * 128 + sub * 8;
#pragma unroll
        for (int ks = 0; ks < 4; ++ks) {
            half8 a0 = *(const half8*)&pt[li][ks * 32 + sub * 8];
            half8 b0 = *(const half8*)(wp + ks * 32);
            half8 b1 = *(const half8*)(wp + 16 * 128 + ks * 32);
            acc2[0] = __builtin_amdgcn_mfma_f32_16x16x32_f16(a0, b0, acc2[0], 0, 0, 0);
            acc2[1] = __builtin_amdgcn_mfma_f32_16x16x32_f16(a0, b1, acc2[1], 0, 0, 0);
        }
        float bv0 = bias[cc + li];
        float bv1 = bias[cc + 16 + li];
#pragma unroll
        for (int g = 0; g < 4; ++g) {
            int r = sub * 4 + g;
            int node = gbase + r;
            if (node < N) {
                Out[(size_t)node * 128 + cc + li]      = fmaxf(acc2[0][g] + bv0, 0.f);
                Out[(size_t)node * 128 + cc + 16 + li] = fmaxf(acc2[1][g] + bv1, 0.f);
            }
        }
    }
}

// ============================================================

extern "C" void kernel_launch(void* const* d_in, const int* in_sizes, int n_in,
                              void* d_out, int out_size, void* d_ws, size_t ws_size,
                              hipStream_t stream)
{
    const float* x     = (const float*)d_in[0];
    const int*   ei    = (const int*)d_in[1];
    const float* W     = (const float*)d_in[2];
    const float* att_s = (const float*)d_in[3];
    const float* att_d = (const float*)d_in[4];
    const float* lin_w = (const float*)d_in[5];
    const float* lin_b = (const float*)d_in[6];
    float* out = (float*)d_out;
    int N = in_sizes[0] / 128;
    int E = in_sizes[1] / 2;

    char* p = (char*)d_ws;
    auto alloc = [&](size_t bytes) { char* r = p; p += (bytes + 255) & ~(size_t)255; return r; };
    f16*    Hh   = (f16*)alloc((size_t)N * 128 * 2);
    f16*    Wt   = (f16*)alloc(128 * 128 * 2);
    f16*    LWt  = (f16*)alloc(128 * 128 * 2);
    float*  AS   = (float*)alloc((size_t)N * 4 * 4);
    float*  AD   = (float*)alloc((size_t)N * 4 * 4);
    int*    deg  = (int*)alloc((size_t)N * 4);
    int*    off  = (int*)alloc((size_t)N * 4);
    int*    btot = (int*)alloc((size_t)NB * 4 * 2);  // btot[NB] + bres[NB]
    int*    bres = btot + NB;
    int*    csr  = (int*)alloc((size_t)E * 4);
    int*    binned = (int*)alloc((size_t)E * 4);

    int hchunk = (E + HBLK - 1) / HBLK;
    int bchunk = (E + BBLK - 1) / BBLK;
    int mb = (N + 63) / 64;
    hipMemsetAsync(btot, 0, (size_t)NB * 4 * 2, stream);
    k_setup<<<128 + HBLK, 256, 0, stream>>>(W, lin_w, Wt, LWt, ei + E, btot, E, hchunk);
    k_gemm_bin<<<mb + BBLK, 256, 0, stream>>>(
        x, Wt, att_s, att_d, Hh, AS, AD, N, mb,
        ei, btot, bres, binned, E, bchunk);
    k_ph_csr<<<NB, 256, 0, stream>>>(binned, btot, csr, off, deg, N, E);
    k_gather_fused<<<(N + 15) / 16, 256, 0, stream>>>(
        (const __half*)Hh, AS, AD, off, deg, csr, LWt, lin_b, out, N);
}